// Round 3
// baseline (8214.990 us; speedup 1.0000x reference)
//
#include <hip/hip_runtime.h>

#define NB 16

__device__ __forceinline__ float sig_(float x) { return 1.0f / (1.0f + __expf(-x)); }
__device__ __forceinline__ float th_(float x)  { return 1.0f - 2.0f / (__expf(2.0f * x) + 1.0f); }

// ---------------------------------------------------------------------------
// Fused NT GEMM: acc[m][g*256+j] = sum_k A[m][k] * Wt[g*256+j][k]
// grid (ceil(M/64), 4), block 256. Tile: 64 m x 64 h-idx (x4 gates = 256 cols).
// mode 0/2: Cout = acc + bias      (emb2 build / gatesB build)
// mode 1:   LSTM token step t: gates = acc + emb2[tok[m][t]]; c,h update,
//           conditional instr_feats write.
// ---------------------------------------------------------------------------
__global__ __launch_bounds__(256, 2)
void gemm_fused(const float* __restrict__ A, const float* __restrict__ Wt,
                const float* __restrict__ bias, float* __restrict__ Cout,
                int M, int mode,
                const int* __restrict__ tok, int t, const float* __restrict__ emb2,
                const int* __restrict__ lengths, float* __restrict__ cbuf,
                float* __restrict__ hout, float* __restrict__ feats)
{
    __shared__ float a_lds[32][64];       // [k][m]
    __shared__ float b_lds[4][32][64];    // [gate][k][r]
    const int tid = threadIdx.x;
    const int tn = tid & 15;              // -> 4 m rows
    const int th = tid >> 4;              // -> 4 h cols
    const int m0 = blockIdx.x * 64;
    const int j0 = blockIdx.y * 64;

    float acc[4][4][4];                   // [gate][hi][ni]
    #pragma unroll
    for (int g = 0; g < 4; ++g)
        #pragma unroll
        for (int x = 0; x < 4; ++x)
            #pragma unroll
            for (int y = 0; y < 4; ++y) acc[g][x][y] = 0.f;

    float4 abuf[2], bbuf[8];
    auto load_t = [&](int k0) {
        #pragma unroll
        for (int p = 0; p < 2; ++p) {
            int idx = tid + p * 256, ml = idx >> 3, k4 = idx & 7;
            int row = m0 + ml;
            abuf[p] = (row < M) ? *(const float4*)&A[row * 256 + k0 + k4 * 4]
                                : make_float4(0.f, 0.f, 0.f, 0.f);
        }
        #pragma unroll
        for (int p = 0; p < 8; ++p) {
            int idx = tid + p * 256;
            int g = idx >> 9, rem = idx & 511, r = rem >> 3, k4 = rem & 7;
            bbuf[p] = *(const float4*)&Wt[(g * 256 + j0 + r) * 256 + k0 + k4 * 4];
        }
    };
    auto store_t = [&]() {
        #pragma unroll
        for (int p = 0; p < 2; ++p) {
            int idx = tid + p * 256, ml = idx >> 3, k4 = idx & 7;
            a_lds[k4 * 4 + 0][ml] = abuf[p].x;
            a_lds[k4 * 4 + 1][ml] = abuf[p].y;
            a_lds[k4 * 4 + 2][ml] = abuf[p].z;
            a_lds[k4 * 4 + 3][ml] = abuf[p].w;
        }
        #pragma unroll
        for (int p = 0; p < 8; ++p) {
            int idx = tid + p * 256;
            int g = idx >> 9, rem = idx & 511, r = rem >> 3, k4 = rem & 7;
            b_lds[g][k4 * 4 + 0][r] = bbuf[p].x;
            b_lds[g][k4 * 4 + 1][r] = bbuf[p].y;
            b_lds[g][k4 * 4 + 2][r] = bbuf[p].z;
            b_lds[g][k4 * 4 + 3][r] = bbuf[p].w;
        }
    };

    load_t(0); store_t(); __syncthreads();
    for (int c = 0; c < 8; ++c) {
        if (c < 7) load_t((c + 1) * 32);  // reg double-buffer: hide global latency
        #pragma unroll 8
        for (int k = 0; k < 32; ++k) {
            float4 a4 = *(const float4*)&a_lds[k][tn * 4];
            float av[4] = {a4.x, a4.y, a4.z, a4.w};
            #pragma unroll
            for (int g = 0; g < 4; ++g) {
                float4 b4 = *(const float4*)&b_lds[g][k][th * 4];
                float bv[4] = {b4.x, b4.y, b4.z, b4.w};
                #pragma unroll
                for (int hi = 0; hi < 4; ++hi)
                    #pragma unroll
                    for (int ni = 0; ni < 4; ++ni)
                        acc[g][hi][ni] += bv[hi] * av[ni];
            }
        }
        __syncthreads();
        if (c < 7) { store_t(); __syncthreads(); }
    }

    const int colb = j0 + th * 4;
    if (mode != 1) {
        float4 bs[4];
        #pragma unroll
        for (int g = 0; g < 4; ++g) bs[g] = *(const float4*)&bias[g * 256 + colb];
        #pragma unroll
        for (int ni = 0; ni < 4; ++ni) {
            int row = m0 + tn * 4 + ni;
            if (row < M) {
                #pragma unroll
                for (int g = 0; g < 4; ++g) {
                    float4 o;
                    o.x = acc[g][0][ni] + bs[g].x;
                    o.y = acc[g][1][ni] + bs[g].y;
                    o.z = acc[g][2][ni] + bs[g].z;
                    o.w = acc[g][3][ni] + bs[g].w;
                    *(float4*)&Cout[row * 1024 + g * 256 + colb] = o;
                }
            }
        }
    } else {
        #pragma unroll
        for (int ni = 0; ni < 4; ++ni) {
            int n = m0 + tn * 4 + ni;
            int v = tok[n * 16 + t];
            const float* e = emb2 + v * 1024 + colb;
            float4 e0 = *(const float4*)(e);
            float4 e1 = *(const float4*)(e + 256);
            float4 e2 = *(const float4*)(e + 512);
            float4 e3 = *(const float4*)(e + 768);
            float4 co = *(const float4*)&cbuf[n * 256 + colb];
            float eg[4][4] = {{e0.x, e0.y, e0.z, e0.w}, {e1.x, e1.y, e1.z, e1.w},
                              {e2.x, e2.y, e2.z, e2.w}, {e3.x, e3.y, e3.z, e3.w}};
            float cold[4] = {co.x, co.y, co.z, co.w};
            float cn[4], hn[4];
            #pragma unroll
            for (int hi = 0; hi < 4; ++hi) {
                float ig = acc[0][hi][ni] + eg[0][hi];
                float fg = acc[1][hi][ni] + eg[1][hi];
                float gg = acc[2][hi][ni] + eg[2][hi];
                float og = acc[3][hi][ni] + eg[3][hi];
                float cc = sig_(fg) * cold[hi] + sig_(ig) * th_(gg);
                cn[hi] = cc;
                hn[hi] = sig_(og) * th_(cc);
            }
            float4 c4 = make_float4(cn[0], cn[1], cn[2], cn[3]);
            float4 h4 = make_float4(hn[0], hn[1], hn[2], hn[3]);
            *(float4*)&cbuf[n * 256 + colb] = c4;
            *(float4*)&hout[n * 256 + colb] = h4;
            if (lengths[n] == t + 1) *(float4*)&feats[n * 256 + colb] = h4;
        }
    }
}

// ---------------------------------------------------------------------------
// Token-LSTM step 0 (h0 = c0 = 0 -> pure pointwise from emb2 gather)
// ---------------------------------------------------------------------------
__global__ __launch_bounds__(256)
void step0_kernel(const int* __restrict__ tok, const int* __restrict__ lengths,
                  const float* __restrict__ emb2, float* __restrict__ cbuf,
                  float* __restrict__ h0, float* __restrict__ feats)
{
    int n = blockIdx.x, j = threadIdx.x;
    int v = tok[n * 16];
    const float* e = emb2 + v * 1024;
    float ig = e[j], gg = e[512 + j], og = e[768 + j];
    float c = sig_(ig) * th_(gg);          // f-gate * c0 drops (c0 = 0)
    float h = sig_(og) * th_(c);
    cbuf[n * 256 + j] = c;
    h0[n * 256 + j] = h;
    if (lengths[n] == 1) feats[n * 256 + j] = h;
}

// ---------------------------------------------------------------------------
// Instruction-LSTM scan: 4096 sequential steps, batch 1, H=256.
// 16 persistent blocks; block b owns h words [b*16, b*16+16).
// Lane map (per 64-lane wave w): lane = g*16 + il*4 + q
//   g  = gate (0..3), il = h-index within wave (0..3), q = k-quarter (0..3)
//   -> wave w fully owns h-indices i4 = w*4+il: quarter-reduce by shfl_xor,
//      gate gather by in-wave shfl. NO gate LDS, NO extra barrier.
// h in LDS: double-buffered + quarter-skewed (quarter q at offset 68*q) so
// the matvec's 4 distinct b128 addresses hit 4 different bank quads.
// Cross-block exchange: data-as-flag hsbuf (pre-set 0xFFFFFFFF = -NaN, h is
// never NaN; single write per word -> any non-NaN is final; relaxed agent
// atomics, no fences). ONE __syncthreads per step.
// ---------------------------------------------------------------------------
__global__ __launch_bounds__(256, 1)
void scan_kernel(const float* __restrict__ gatesB, const float* __restrict__ Whh,
                 const float* __restrict__ linW, const float* __restrict__ linb,
                 float* __restrict__ hsbuf, float* __restrict__ out)
{
    const int b    = blockIdx.x;
    const int tid  = threadIdx.x;
    const int w    = tid >> 6;            // wave 0..3
    const int lane = tid & 63;
    const int g    = lane >> 4;           // gate
    const int il   = (lane >> 2) & 3;     // h-index within wave
    const int q    = lane & 3;            // k-quarter
    const int i4   = w * 4 + il;          // h-index within block
    const int hw   = b * 16 + i4;         // global h word this lane produces

    __shared__ float h_buf[2][4 * 68];    // double-buffered, quarter-skewed
    __shared__ float red_lds[4];

    // W slice -> registers: row g*256 + hw, cols q*64 .. q*64+63
    float4 w_reg[16];
    {
        const float* wp = Whh + (g * 256 + hw) * 256 + q * 64;
        #pragma unroll
        for (int kk = 0; kk < 16; ++kk) w_reg[kk] = *(const float4*)&wp[kk * 4];
    }
    if (tid < 136) { h_buf[0][tid] = 0.f; h_buf[0][tid + 136] = 0.f; }  // h_0 = 0
    float c_reg = 0.f;                    // c for index i4 (replicated x16 lanes)
    const bool mine      = (tid >> 4) == b;               // poll map: tid<->word tid
    const int  skew_own  = (hw  >> 6) * 68 + (hw  & 63);
    const int  skew_poll = (tid >> 6) * 68 + (tid & 63);
    const bool producer  = (lane == il * 4);              // g==0 && q==0
    __syncthreads();

    for (int s = 0; s < 4096; ++s) {
        const int rb = s & 1;
        // prefetch gate bias for (g, hw) — independent of h, overlaps matvec
        float bg = gatesB[s * 1024 + g * 256 + hw];
        // matvec: this lane covers k = q*64 .. q*64+63, W in registers
        const float* hq = &h_buf[rb][q * 68];
        float4 ac = make_float4(0.f, 0.f, 0.f, 0.f);
        #pragma unroll
        for (int kk = 0; kk < 16; ++kk) {
            float4 h4 = *(const float4*)&hq[kk * 4];
            ac.x += w_reg[kk].x * h4.x;
            ac.y += w_reg[kk].y * h4.y;
            ac.z += w_reg[kk].z * h4.z;
            ac.w += w_reg[kk].w * h4.w;
        }
        float sum = (ac.x + ac.y) + (ac.z + ac.w);
        sum += __shfl_xor(sum, 1);
        sum += __shfl_xor(sum, 2);        // full row sum in all 4 q-lanes
        float gval = sum + bg;
        // gather the 4 gate values for my h-index (in-wave shfl)
        float igv = __shfl(gval,      il * 4);
        float fgv = __shfl(gval, 16 + il * 4);
        float ggv = __shfl(gval, 32 + il * 4);
        float ogv = __shfl(gval, 48 + il * 4);
        float cc = sig_(fgv) * c_reg + sig_(igv) * th_(ggv);
        c_reg = cc;
        float hh = sig_(ogv) * th_(cc);
        if (producer) {                   // publish ASAP: remote critical path
            __hip_atomic_store(&hsbuf[(s + 1) * 256 + hw], hh,
                               __ATOMIC_RELAXED, __HIP_MEMORY_SCOPE_AGENT);
            h_buf[rb ^ 1][skew_own] = hh;
        }
        if (!mine) {
            const unsigned* p = (const unsigned*)&hsbuf[(s + 1) * 256 + tid];
            unsigned u = __hip_atomic_load(p, __ATOMIC_RELAXED,
                                           __HIP_MEMORY_SCOPE_AGENT);
            while (u == 0xFFFFFFFFu) {
                __builtin_amdgcn_s_sleep(1);
                u = __hip_atomic_load(p, __ATOMIC_RELAXED,
                                      __HIP_MEMORY_SCOPE_AGENT);
            }
            h_buf[rb ^ 1][skew_poll] = __uint_as_float(u);
        }
        __syncthreads();
    }

    if (b == 0) {                         // out = h_T . lin_W + lin_b
        float p = h_buf[0][skew_poll] * linW[tid];   // h word `tid`
        #pragma unroll
        for (int off = 1; off < 64; off <<= 1) p += __shfl_xor(p, off);
        if ((tid & 63) == 0) red_lds[tid >> 6] = p;
        __syncthreads();
        if (tid == 0) out[0] = red_lds[0] + red_lds[1] + red_lds[2] + red_lds[3] + linb[0];
    }
}

extern "C" void kernel_launch(void* const* d_in, const int* in_sizes, int n_in,
                              void* d_out, int out_size, void* d_ws, size_t ws_size,
                              hipStream_t stream)
{
    const int*   tok  = (const int*)d_in[0];
    const int*   len  = (const int*)d_in[1];
    const float* emb  = (const float*)d_in[2];
    const float* tWih = (const float*)d_in[3];
    const float* tWhh = (const float*)d_in[4];
    const float* tb   = (const float*)d_in[5];
    const float* iWih = (const float*)d_in[6];
    const float* iWhh = (const float*)d_in[7];
    const float* ib   = (const float*)d_in[8];
    const float* lW   = (const float*)d_in[9];
    const float* lb   = (const float*)d_in[10];
    float* out = (float*)d_out;

    // workspace layout (floats): ~44 MiB total
    float* emb2   = (float*)d_ws;           // [2000][1024]
    float* hbuf0  = emb2  + 2048000;        // [4096][256] ping
    float* hbuf1  = hbuf0 + 1048576;        // [4096][256] pong
    float* cbuf   = hbuf1 + 1048576;        // [4096][256]
    float* feats  = cbuf  + 1048576;        // [4096][256]
    float* gatesB = feats + 1048576;        // [4096][1024]
    float* hsbuf  = gatesB + 4194304;       // [4097][256] data-as-flag buffer

    // sentinel init: 0xFF bytes -> 0xFFFFFFFF (-NaN) in every hsbuf word
    hipMemsetAsync(hsbuf, 0xFF, (size_t)4097 * 256 * sizeof(float), stream);

    // emb2 = emb @ tok_W_ih^T + tok_b  (V=2000 rows)
    gemm_fused<<<dim3(32, 4), 256, 0, stream>>>(emb, tWih, tb, emb2, 2000, 0,
                                                nullptr, 0, nullptr, nullptr,
                                                nullptr, nullptr, nullptr);
    // token LSTM step 0 (pointwise)
    step0_kernel<<<4096, 256, 0, stream>>>(tok, len, emb2, cbuf, hbuf0, feats);
    // token LSTM steps 1..15 (fused GEMM + gather + activations)
    for (int t = 1; t < 16; ++t) {
        float* hprev = (t & 1) ? hbuf0 : hbuf1;
        float* hcur  = (t & 1) ? hbuf1 : hbuf0;
        gemm_fused<<<dim3(64, 4), 256, 0, stream>>>(hprev, tWhh, nullptr, nullptr,
                                                    4096, 1, tok, t, emb2, len,
                                                    cbuf, hcur, feats);
    }
    // gatesB = instr_feats @ ins_W_ih^T + ins_b
    gemm_fused<<<dim3(64, 4), 256, 0, stream>>>(feats, iWih, ib, gatesB, 4096, 2,
                                                nullptr, 0, nullptr, nullptr,
                                                nullptr, nullptr, nullptr);
    // 4096-step sequential instruction LSTM + final linear
    scan_kernel<<<NB, 256, 0, stream>>>(gatesB, iWhh, lW, lb, hsbuf, out);
}